// Round 1
// baseline (383.299 us; speedup 1.0000x reference)
//
#include <hip/hip_runtime.h>

// ParametricInhibition: out[b,i,h,w] = sum_j inv(I - tpl)[i,j] * act[b,j,h,w]
// tpl circulant(256) -> M = inv(I-tpl) circulant; m = IDFT(1/(1-DFT(c))) via
// 256-pt cosine transforms. Einsum = GEMM M(256x256) x act(256x200704).
//
// v2: barrier-free streaming GEMM. 32x32x16 f16 MFMA's B-fragment is loaded
// DIRECTLY from global ([k][p] layout, lane l&31 -> p contiguous = 128B
// segments), so no LDS transpose, no __syncthreads, no vmcnt(0) drain.
// Each wave: 64 out-ch x 64 px, software-pipelined (v0/v1) k-loop.
// Stores are nontemporal (out never re-read; keeps act resident in L3).

#define IN_CH 256
#define HW    3136          // 56*56
#define TP    64            // pixels per block (49 tiles * 64 = 3136)

typedef _Float16 f16x8  __attribute__((ext_vector_type(8)));
typedef float    f32x16 __attribute__((ext_vector_type(16)));

// d_ws: [0, 131072) : A-frags fp16 for mfma_f32_32x32x16_f16,
//   layout [s(16)][t(8)][lane(64)][j(8)], t = 32-channel tile index.

// ---------------- kernel 1: m[256] + 32x32 A-fragment table ----------------
__global__ __launch_bounds__(256) void pi_build(const float* __restrict__ damp,
                                                const float* __restrict__ width,
                                                f16x8* __restrict__ afrag) {
    __shared__ float cS[256], gS[256], ctab[256], mS[256];
    int t = threadIdx.x;
    float w = width[0], dmp = damp[0];

    // exact-angle cos table: index is (k*n) & 255
    ctab[t] = cosf((float)t * 0.0245436926f /* 2*pi/256 */);

    // first column of tpl (center tap zeroed, tails wrap)
    int x = (t < 128) ? t : t - 256;
    float cv = 0.0f;
    if (t != 0 && x >= -31 && x <= 31) {
        float fx2 = (float)(x * x);
        float w2  = w * w;
        cv = dmp * (1.0f - fx2 / w2) * expf(-fx2 / (2.0f * w2));
    }
    cS[t] = cv;
    __syncthreads();

    float lam = 0.0f;
#pragma unroll 8
    for (int n = 0; n < 256; n++) lam += cS[n] * ctab[(t * n) & 255];
    gS[t] = 1.0f / (1.0f - lam);
    __syncthreads();

    float md = 0.0f;
#pragma unroll 8
    for (int k = 0; k < 256; k++) md += gS[k] * ctab[(t * k) & 255];
    mS[t] = md * (1.0f / 256.0f);
    __syncthreads();

    // A-frag layout (mfma_f32_32x32x16_f16): lane l holds A[m=l&31][k=8*(l>>5)+j]
#pragma unroll
    for (int g = 0; g < 32; g++) {
        int gid = g * 256 + t;                 // [0, 8192)
        int l  = gid & 63;
        int tt = (gid >> 6) & 7;               // 32-ch tile
        int s  = gid >> 9;                     // k-step of 16
        int i     = 32 * tt + (l & 31);
        int kbase = 16 * s + 8 * (l >> 5);
        f16x8 h;
#pragma unroll
        for (int j = 0; j < 8; j++)
            h[j] = (_Float16)mS[(i - (kbase + j)) & 255];   // M[i][k] = m[(i-k)&255]
        afrag[gid] = h;
    }
}

// ---------------- kernel 2: barrier-free GEMM ----------------
__device__ __forceinline__ void loads16(const float* __restrict__ src, float* v) {
    // 16 global_load_dword, each = 2 x 128B contiguous segments
#pragma unroll
    for (int j = 0; j < 8; j++) {
        v[j]     = src[(size_t)j * HW];
        v[8 + j] = src[(size_t)j * HW + 32];
    }
}

__device__ __forceinline__ void compute16(const float* v,
                                          const f16x8* __restrict__ afrag,
                                          int base, int lane,
                                          f32x16 acc[2][2]) {
    f16x8 b0, b1;
#pragma unroll
    for (int j = 0; j < 8; j++) {
        b0[j] = (_Float16)v[j];
        b1[j] = (_Float16)v[8 + j];
    }
    f16x8 a0 = afrag[(base + 0) * 64 + lane];   // L2-hot 128 KB table
    f16x8 a1 = afrag[(base + 1) * 64 + lane];
    acc[0][0] = __builtin_amdgcn_mfma_f32_32x32x16_f16(a0, b0, acc[0][0], 0, 0, 0);
    acc[0][1] = __builtin_amdgcn_mfma_f32_32x32x16_f16(a0, b1, acc[0][1], 0, 0, 0);
    acc[1][0] = __builtin_amdgcn_mfma_f32_32x32x16_f16(a1, b0, acc[1][0], 0, 0, 0);
    acc[1][1] = __builtin_amdgcn_mfma_f32_32x32x16_f16(a1, b1, acc[1][1], 0, 0, 0);
}

__global__ __launch_bounds__(256, 4) void pi_gemm(const float* __restrict__ act,
                                                  float* __restrict__ out,
                                                  const f16x8* __restrict__ afrag) {
    int tid  = threadIdx.x;
    int lane = tid & 63;
    int wv   = tid >> 6;          // wave owns out-channels [64*wv, 64*wv+64)

    int b    = blockIdx.x / 49;
    int tile = blockIdx.x - b * 49;
    int p0   = tile * TP;

    int col   = lane & 31;
    int khalf = (lane >> 5) * 8;

    const float* actb = act + (size_t)b * (IN_CH * HW) + p0 + col;
    float*       outb = out + (size_t)b * (IN_CH * HW) + p0 + col;

    f32x16 acc[2][2] = {};

    float v0[16], v1[16];
    const float* ksrc = actb + (size_t)khalf * HW;

    loads16(ksrc, v0);
#pragma unroll
    for (int ss = 0; ss < 8; ss++) {
        loads16(ksrc + (size_t)(16 * (2 * ss + 1)) * HW, v1);
        compute16(v0, afrag, (2 * ss) * 8 + 2 * wv, lane, acc);
        if (ss < 7)
            loads16(ksrc + (size_t)(16 * (2 * ss + 2)) * HW, v0);
        compute16(v1, afrag, (2 * ss + 1) * 8 + 2 * wv, lane, acc);
    }

    // epilogue: C/D layout col = lane&31, row = (r&3) + 8*(r>>2) + 4*(lane>>5)
    int rb = 4 * (lane >> 5);
#pragma unroll
    for (int ti = 0; ti < 2; ti++) {
#pragma unroll
        for (int ni = 0; ni < 2; ni++) {
            float* dst = outb + (size_t)(64 * wv + 32 * ti + rb) * HW + 32 * ni;
#pragma unroll
            for (int r = 0; r < 16; r++) {
                int row = (r & 3) + 8 * (r >> 2);
                __builtin_nontemporal_store(acc[ti][ni][r], dst + (size_t)row * HW);
            }
        }
    }
}

extern "C" void kernel_launch(void* const* d_in, const int* in_sizes, int n_in,
                              void* d_out, int out_size, void* d_ws, size_t ws_size,
                              hipStream_t stream) {
    const float* act   = (const float*)d_in[0];
    const float* damp  = (const float*)d_in[1];
    const float* width = (const float*)d_in[2];
    float* out = (float*)d_out;

    f16x8* afrag = (f16x8*)d_ws;
    int batches = in_sizes[0] / (IN_CH * HW);   // 64

    pi_build<<<1, 256, 0, stream>>>(damp, width, afrag);
    pi_gemm<<<batches * 49, 256, 0, stream>>>(act, out, afrag);
}

// Round 2
// 364.524 us; speedup vs baseline: 1.0515x; 1.0515x over previous
//
#include <hip/hip_runtime.h>

// ParametricInhibition: out[b,i,h,w] = sum_j inv(I - tpl)[i,j] * act[b,j,h,w]
// tpl circulant(256) -> M = inv(I-tpl) circulant; m = IDFT(1/(1-DFT(c))) via
// 256-pt cosine transforms. Einsum = GEMM M(256x256) x act(256x200704).
//
// v3: LDS ring pipeline (T3+T4). Block = 64 px x 256 out-ch, 4 waves split M.
// act tile staged ONCE per block via global_load_lds dwordx4 into a 4-deep
// ring of [32k][64px] f32 buffers (32 KB). Counted s_waitcnt vmcnt(4) + raw
// s_barrier per k-step -- loads for 3 future steps stay in flight across
// barriers (never drain to 0 in the loop). B-frags: 32x ds_read_b32/step
// (2 lanes/bank = free), cvt f32->f16 at read. MFMA 32x32x16_f16, acc in
// AGPRs. Nontemporal stores (out never re-read; keep act L3-resident).

#define IN_CH 256
#define HW    3136          // 56*56
#define TP    64            // pixels per block (49 tiles * 64 = 3136)
#define KS    32            // k-channels per step; 8 steps

typedef _Float16 f16x8  __attribute__((ext_vector_type(8)));
typedef float    f32x16 __attribute__((ext_vector_type(16)));
typedef unsigned int u32;

// d_ws: [0, 131072) : A-frags fp16 for mfma_f32_32x32x16_f16,
//   layout [s(16)][t(8)][lane(64)][j(8)], s = k-slice of 16, t = 32-ch out tile.

// ---------------- kernel 1: m[256] + 32x32 A-fragment table ----------------
__global__ __launch_bounds__(256) void pi_build(const float* __restrict__ damp,
                                                const float* __restrict__ width,
                                                f16x8* __restrict__ afrag) {
    __shared__ float cS[256], gS[256], ctab[256], mS[256];
    int t = threadIdx.x;
    float w = width[0], dmp = damp[0];

    // exact-angle cos table: index is (k*n) & 255
    ctab[t] = cosf((float)t * 0.0245436926f /* 2*pi/256 */);

    // first column of tpl (center tap zeroed, tails wrap)
    int x = (t < 128) ? t : t - 256;
    float cv = 0.0f;
    if (t != 0 && x >= -31 && x <= 31) {
        float fx2 = (float)(x * x);
        float w2  = w * w;
        cv = dmp * (1.0f - fx2 / w2) * expf(-fx2 / (2.0f * w2));
    }
    cS[t] = cv;
    __syncthreads();

    float lam = 0.0f;
#pragma unroll 8
    for (int n = 0; n < 256; n++) lam += cS[n] * ctab[(t * n) & 255];
    gS[t] = 1.0f / (1.0f - lam);
    __syncthreads();

    float md = 0.0f;
#pragma unroll 8
    for (int k = 0; k < 256; k++) md += gS[k] * ctab[(t * k) & 255];
    mS[t] = md * (1.0f / 256.0f);
    __syncthreads();

    // A-frag layout (mfma_f32_32x32x16_f16): lane l holds A[m=l&31][k=8*(l>>5)+j]
#pragma unroll
    for (int g = 0; g < 32; g++) {
        int gid = g * 256 + t;                 // [0, 8192)
        int l  = gid & 63;
        int tt = (gid >> 6) & 7;               // 32-ch out tile
        int s  = gid >> 9;                     // k-slice of 16
        int i     = 32 * tt + (l & 31);
        int kbase = 16 * s + 8 * (l >> 5);
        f16x8 h;
#pragma unroll
        for (int j = 0; j < 8; j++)
            h[j] = (_Float16)mS[(i - (kbase + j)) & 255];   // M[i][k] = m[(i-k)&255]
        afrag[gid] = h;
    }
}

// ---------------- kernel 2: ring-pipelined GEMM ----------------
__device__ __forceinline__ void gl_lds16(const float* g, const float* l) {
    // 16B per lane: global per-lane addr -> LDS wave-uniform base + lane*16
    __builtin_amdgcn_global_load_lds(
        (const __attribute__((address_space(1))) u32*)g,
        (__attribute__((address_space(3))) u32*)l, 16, 0, 0);
}

__global__ __launch_bounds__(256, 4) void pi_gemm(const float* __restrict__ act,
                                                  float* __restrict__ out,
                                                  const f16x8* __restrict__ afrag) {
    __shared__ float lds[4][KS][TP];   // 4-deep ring, 8 KB per step, 32 KB

    int tid  = threadIdx.x;
    int lane = tid & 63;
    int wv   = tid >> 6;          // wave owns out-channels [64*wv, 64*wv+64)

    int b    = blockIdx.x / 49;
    int tile = blockIdx.x - b * 49;
    int p0   = tile * TP;

    const float* actb = act + (size_t)b * (IN_CH * HW) + p0;
    float*       outb = out + (size_t)b * (IN_CH * HW) + p0;

    // staging: wave wv covers k-rows [8*wv, 8*wv+8) of each 32-row step buffer,
    // as 2 global_load_lds_dwordx4 (1 KB each). lane l -> k-row +(l>>4), px 4*(l&15).
    const float* gsrc = actb + (size_t)(lane >> 4) * HW + (lane & 15) * 4;

    int lo = lane & 31;
    int hi = lane >> 5;

    f32x16 acc[2][2] = {};

#define STAGE(st) do {                                                         \
    gl_lds16(gsrc + (size_t)((st) * KS + 8 * wv    ) * HW,                     \
             &lds[(st) & 3][8 * wv    ][0]);                                   \
    gl_lds16(gsrc + (size_t)((st) * KS + 8 * wv + 4) * HW,                     \
             &lds[(st) & 3][8 * wv + 4][0]);                                   \
} while (0)

// counted wait (own loads for buffer t done) + barrier (everyone's done).
// asm "memory" clobber blocks IR-level motion of LDS ops across the fence;
// sched_barrier(0) blocks machine-scheduler motion (rule #18/#21).
#define WAITB(N) do {                                                          \
    __builtin_amdgcn_sched_barrier(0);                                         \
    asm volatile("s_waitcnt vmcnt(" #N ")" ::: "memory");                      \
    __builtin_amdgcn_s_barrier();                                              \
    __builtin_amdgcn_sched_barrier(0);                                         \
} while (0)

#define KSTEP(t) do {                                                          \
    const float (*buf)[TP] = lds[(t) & 3];                                     \
    f16x8 bf0[2], bf1[2];                                                      \
    _Pragma("unroll")                                                          \
    for (int s = 0; s < 2; s++) {                                              \
        _Pragma("unroll")                                                      \
        for (int j = 0; j < 8; j++) {                                          \
            bf0[s][j] = (_Float16)buf[16 * s + 8 * hi + j][lo];                \
            bf1[s][j] = (_Float16)buf[16 * s + 8 * hi + j][32 + lo];           \
        }                                                                      \
    }                                                                          \
    _Pragma("unroll")                                                          \
    for (int s = 0; s < 2; s++) {                                              \
        f16x8 a0 = afrag[((2 * (t) + s) * 8 + 2 * wv    ) * 64 + lane];        \
        f16x8 a1 = afrag[((2 * (t) + s) * 8 + 2 * wv + 1) * 64 + lane];        \
        acc[0][0] = __builtin_amdgcn_mfma_f32_32x32x16_f16(a0, bf0[s], acc[0][0], 0, 0, 0); \
        acc[0][1] = __builtin_amdgcn_mfma_f32_32x32x16_f16(a0, bf1[s], acc[0][1], 0, 0, 0); \
        acc[1][0] = __builtin_amdgcn_mfma_f32_32x32x16_f16(a1, bf0[s], acc[1][0], 0, 0, 0); \
        acc[1][1] = __builtin_amdgcn_mfma_f32_32x32x16_f16(a1, bf1[s], acc[1][1], 0, 0, 0); \
    }                                                                          \
} while (0)

    // prologue: 3 step-buffers in flight (6 gload_lds per wave)
    STAGE(0); STAGE(1); STAGE(2);

    // main: wait own buffer-t loads (leave t+1,t+2 in flight), barrier,
    // prefetch t+3 (victim slot = t-1, consumed last iter), compute t.
    WAITB(4); STAGE(3); KSTEP(0);
    WAITB(4); STAGE(4); KSTEP(1);
    WAITB(4); STAGE(5); KSTEP(2);
    WAITB(4); STAGE(6); KSTEP(3);
    WAITB(4); STAGE(7); KSTEP(4);
    WAITB(4);           KSTEP(5);
    WAITB(2);           KSTEP(6);
    WAITB(0);           KSTEP(7);

#undef STAGE
#undef WAITB
#undef KSTEP

    // epilogue: C/D layout col = lane&31, row = (r&3) + 8*(r>>2) + 4*(lane>>5)
    int rb = 4 * hi;
#pragma unroll
    for (int ti = 0; ti < 2; ti++) {
#pragma unroll
        for (int ni = 0; ni < 2; ni++) {
            float* dst = outb + (size_t)(64 * wv + 32 * ti + rb) * HW + 32 * ni + lo;
#pragma unroll
            for (int r = 0; r < 16; r++) {
                int row = (r & 3) + 8 * (r >> 2);
                __builtin_nontemporal_store(acc[ti][ni][r], dst + (size_t)row * HW);
            }
        }
    }
}

extern "C" void kernel_launch(void* const* d_in, const int* in_sizes, int n_in,
                              void* d_out, int out_size, void* d_ws, size_t ws_size,
                              hipStream_t stream) {
    const float* act   = (const float*)d_in[0];
    const float* damp  = (const float*)d_in[1];
    const float* width = (const float*)d_in[2];
    float* out = (float*)d_out;

    f16x8* afrag = (f16x8*)d_ws;
    int batches = in_sizes[0] / (IN_CH * HW);   // 64

    pi_build<<<1, 256, 0, stream>>>(damp, width, afrag);
    pi_gemm<<<batches * 49, 256, 0, stream>>>(act, out, afrag);
}

// Round 3
// 363.806 us; speedup vs baseline: 1.0536x; 1.0020x over previous
//
#include <hip/hip_runtime.h>

// ParametricInhibition: out[b,i,h,w] = sum_j inv(I - tpl)[i,j] * act[b,j,h,w]
// tpl circulant(256) -> M = inv(I-tpl) circulant; m = IDFT(1/(1-DFT(c))) via
// 256-pt cosine transforms. Einsum = GEMM M(256x256) x act(256x200704).
//
// v4: A-IN-REGISTERS ring pipeline. v1-v3 all fetched A-fragments from global
// inside the k-loop; those loads poison vmcnt so every counted wait drained
// the freshly-issued stage loads (depth-0 pipeline, ~900cy exposed per step).
// Fix: wave owns 32 out-ch; its whole A-operand = 16 f16x8 = 64 VGPR,
// preloaded once. Inner loop vmem = ONLY the 2 global_load_lds/step ->
// vmcnt(4) keeps 2-3 step buffers in flight across barriers for real.
// Block = 128 out-ch x 64 px, grid 6272 (ch-half fastest -> tile pair shares
// L2/L3). Nontemporal stores.

#define IN_CH 256
#define HW    3136          // 56*56
#define TP    64            // pixels per block tile
#define KS    32            // k-channels per step; 8 steps

typedef _Float16 f16x8  __attribute__((ext_vector_type(8)));
typedef float    f32x16 __attribute__((ext_vector_type(16)));
typedef unsigned int u32;

// d_ws: [0, 131072) : A-frags fp16 for mfma_f32_32x32x16_f16,
//   layout [s(16)][t(8)][lane(64)][j(8)], s = k-slice of 16, t = 32-ch out tile.

// ---------------- kernel 1: m[256] + 32x32 A-fragment table ----------------
__global__ __launch_bounds__(256) void pi_build(const float* __restrict__ damp,
                                                const float* __restrict__ width,
                                                f16x8* __restrict__ afrag) {
    __shared__ float cS[256], gS[256], ctab[256], mS[256];
    int t = threadIdx.x;
    float w = width[0], dmp = damp[0];

    // exact-angle cos table: index is (k*n) & 255
    ctab[t] = cosf((float)t * 0.0245436926f /* 2*pi/256 */);

    // first column of tpl (center tap zeroed, tails wrap)
    int x = (t < 128) ? t : t - 256;
    float cv = 0.0f;
    if (t != 0 && x >= -31 && x <= 31) {
        float fx2 = (float)(x * x);
        float w2  = w * w;
        cv = dmp * (1.0f - fx2 / w2) * expf(-fx2 / (2.0f * w2));
    }
    cS[t] = cv;
    __syncthreads();

    float lam = 0.0f;
#pragma unroll 8
    for (int n = 0; n < 256; n++) lam += cS[n] * ctab[(t * n) & 255];
    gS[t] = 1.0f / (1.0f - lam);
    __syncthreads();

    float md = 0.0f;
#pragma unroll 8
    for (int k = 0; k < 256; k++) md += gS[k] * ctab[(t * k) & 255];
    mS[t] = md * (1.0f / 256.0f);
    __syncthreads();

    // A-frag layout (mfma_f32_32x32x16_f16): lane l holds A[m=l&31][k=8*(l>>5)+j]
#pragma unroll
    for (int g = 0; g < 32; g++) {
        int gid = g * 256 + t;                 // [0, 8192)
        int l  = gid & 63;
        int tt = (gid >> 6) & 7;               // 32-ch out tile
        int s  = gid >> 9;                     // k-slice of 16
        int i     = 32 * tt + (l & 31);
        int kbase = 16 * s + 8 * (l >> 5);
        f16x8 h;
#pragma unroll
        for (int j = 0; j < 8; j++)
            h[j] = (_Float16)mS[(i - (kbase + j)) & 255];   // M[i][k] = m[(i-k)&255]
        afrag[gid] = h;
    }
}

// ---------------- kernel 2: A-in-reg ring-pipelined GEMM ----------------
__device__ __forceinline__ void gl_lds16(const float* g, const float* l) {
    // 16B per lane: global per-lane addr -> LDS wave-uniform base + lane*16
    __builtin_amdgcn_global_load_lds(
        (const __attribute__((address_space(1))) u32*)g,
        (__attribute__((address_space(3))) u32*)l, 16, 0, 0);
}

__global__ __launch_bounds__(256, 4) void pi_gemm(const float* __restrict__ act,
                                                  float* __restrict__ out,
                                                  const f16x8* __restrict__ afrag) {
    __shared__ float lds[4][KS][TP];   // 4-deep ring, 8 KB per step, 32 KB

    int tid  = threadIdx.x;
    int lane = tid & 63;
    int wv   = tid >> 6;

    // grid: [ch-half (2)] fastest, then [49 px tiles] x [64 batches]
    int bid  = blockIdx.x;
    int h    = bid & 1;
    int bt   = bid >> 1;
    int b    = bt / 49;
    int tile = bt - b * 49;
    int p0   = tile * TP;
    int t    = 4 * h + wv;        // this wave's 32-out-ch tile index (0..7)

    const float* actb = act + (size_t)b * (IN_CH * HW) + p0;
    float*       outb = out + (size_t)b * (IN_CH * HW) + p0;

    int lo = lane & 31;
    int hi = lane >> 5;

    // ---- A preload: whole wave-operand in registers (16 x f16x8 = 64 VGPR)
    f16x8 ar[16];
#pragma unroll
    for (int s = 0; s < 16; s++)
        ar[s] = afrag[(s * 8 + t) * 64 + lane];

    // staging: wave wv covers k-rows [8*wv, 8*wv+8) of each step buffer,
    // as 2 global_load_lds_dwordx4. lane l -> k-row +(l>>4), px 4*(l&15).
    const float* gsrc = actb + (size_t)(lane >> 4) * HW + (lane & 15) * 4;

    f32x16 acc[2] = {};

#define STAGE(st) do {                                                         \
    gl_lds16(gsrc + (size_t)((st) * KS + 8 * wv    ) * HW,                     \
             &lds[(st) & 3][8 * wv    ][0]);                                   \
    gl_lds16(gsrc + (size_t)((st) * KS + 8 * wv + 4) * HW,                     \
             &lds[(st) & 3][8 * wv + 4][0]);                                   \
} while (0)

#define WAITB(N) do {                                                          \
    __builtin_amdgcn_sched_barrier(0);                                         \
    asm volatile("s_waitcnt vmcnt(" #N ")" ::: "memory");                      \
    __builtin_amdgcn_s_barrier();                                              \
    __builtin_amdgcn_sched_barrier(0);                                         \
} while (0)

#define KSTEP(kk) do {                                                         \
    const float (*buf)[TP] = lds[(kk) & 3];                                    \
    _Pragma("unroll")                                                          \
    for (int s = 0; s < 2; s++) {                                              \
        f16x8 b0, b1;                                                          \
        _Pragma("unroll")                                                      \
        for (int j = 0; j < 8; j++) {                                          \
            b0[j] = (_Float16)buf[16 * s + 8 * hi + j][lo];                    \
            b1[j] = (_Float16)buf[16 * s + 8 * hi + j][32 + lo];               \
        }                                                                      \
        acc[0] = __builtin_amdgcn_mfma_f32_32x32x16_f16(ar[2 * (kk) + s], b0, acc[0], 0, 0, 0); \
        acc[1] = __builtin_amdgcn_mfma_f32_32x32x16_f16(ar[2 * (kk) + s], b1, acc[1], 0, 0, 0); \
    }                                                                          \
} while (0)

    // prologue: issue A loads (16) then 3 step-buffers (6). vmcnt(4) drains
    // afrag + stage0, leaves stage1,2 in flight.
    STAGE(0); STAGE(1); STAGE(2);

    WAITB(4); STAGE(3); KSTEP(0);
    WAITB(4); STAGE(4); KSTEP(1);
    WAITB(4); STAGE(5); KSTEP(2);
    WAITB(4); STAGE(6); KSTEP(3);
    WAITB(4); STAGE(7); KSTEP(4);
    WAITB(4);           KSTEP(5);
    WAITB(2);           KSTEP(6);
    WAITB(0);           KSTEP(7);

#undef STAGE
#undef WAITB
#undef KSTEP

    // epilogue: C/D layout col = lane&31, row = (r&3) + 8*(r>>2) + 4*(lane>>5)
    int rb = 4 * hi;
#pragma unroll
    for (int ni = 0; ni < 2; ni++) {
        float* dst = outb + (size_t)(32 * t + rb) * HW + 32 * ni + lo;
#pragma unroll
        for (int r = 0; r < 16; r++) {
            int row = (r & 3) + 8 * (r >> 2);
            __builtin_nontemporal_store(acc[ni][r], dst + (size_t)row * HW);
        }
    }
}

extern "C" void kernel_launch(void* const* d_in, const int* in_sizes, int n_in,
                              void* d_out, int out_size, void* d_ws, size_t ws_size,
                              hipStream_t stream) {
    const float* act   = (const float*)d_in[0];
    const float* damp  = (const float*)d_in[1];
    const float* width = (const float*)d_in[2];
    float* out = (float*)d_out;

    f16x8* afrag = (f16x8*)d_ws;
    int batches = in_sizes[0] / (IN_CH * HW);   // 64

    pi_build<<<1, 256, 0, stream>>>(damp, width, afrag);
    pi_gemm<<<batches * 49 * 2, 256, 0, stream>>>(act, out, afrag);
}